// Round 8
// baseline (237.230 us; speedup 1.0000x reference)
//
#include <hip/hip_runtime.h>
#include <math.h>

#define NROWS 8192
#define DIM   1024
#define BT    256              // logical tile edge (column span of a block)
#define SLOTS 64               // top2 slots per row: 2 per column-chunk
#define NTRI  528              // 32*33/2 lower-triangle tiles
#define NBLK  1056             // 528 tiles x 2 row-halves
#define NKT   32               // 1024 / BK
#define BK    32               // K per step (64 B per row)

typedef __bf16 bf16x8 __attribute__((ext_vector_type(8)));
typedef float  f32x4  __attribute__((ext_vector_type(4)));

// fp32 -> bf16 (RNE)
__device__ __forceinline__ unsigned short f2bf(float f) {
    unsigned int u = __float_as_uint(f);
    u = (u + 0x7FFFu + ((u >> 16) & 1u)) >> 16;
    return (unsigned short)u;
}

__device__ __forceinline__ void gld16(const void* g, void* l) {
    __builtin_amdgcn_global_load_lds(
        (__attribute__((address_space(1))) void*)g,
        (__attribute__((address_space(3))) void*)l,
        16, 0, 0);
}

template<int N>
__device__ __forceinline__ float dppror(float v) {
    return __int_as_float(__builtin_amdgcn_update_dpp(
        0, __float_as_int(v), 0x120 + N, 0xF, 0xF, false));
}

__device__ __forceinline__ void t2push(float& a1, float& a2, float v) {
    float hi = fmaxf(a1, v);
    float lo = fminf(a1, v);
    a1 = hi;
    a2 = fmaxf(a2, lo);
}

__device__ __forceinline__ void t2merge(float& a1, float& a2, float b1, float b2) {
    float hi = fmaxf(a1, b1);
    float lo = fminf(a1, b1);
    a1 = hi;
    a2 = fmaxf(fmaxf(a2, b2), lo);
}

// ---- Kernel A: row L2-normalize fp32->bf16; block 0 zeroes the reduce cell ----
__global__ __launch_bounds__(256) void knorm(const float* __restrict__ x,
                                             unsigned short* __restrict__ xn,
                                             float* __restrict__ red) {
    if (blockIdx.x == 0 && threadIdx.x == 0) {
        red[0] = 0.0f;                 // sum(loss*gate)
        red[1] = 0.0f;                 // sum(gate)
        ((unsigned int*)red)[2] = 0u;  // block counter
    }
    const int w = threadIdx.x >> 6, lane = threadIdx.x & 63;
    const int row = blockIdx.x * 4 + w;
    const float4* src = (const float4*)(x + (size_t)row * DIM);
    float4 v[4];
    float ss = 0.0f;
    #pragma unroll
    for (int i = 0; i < 4; i++) {
        v[i] = src[lane + 64 * i];
        ss += v[i].x * v[i].x + v[i].y * v[i].y + v[i].z * v[i].z + v[i].w * v[i].w;
    }
    #pragma unroll
    for (int d = 1; d < 64; d <<= 1) ss += __shfl_xor(ss, d);
    const float inv = 1.0f / fmaxf(sqrtf(ss), 1e-8f);
    unsigned short* dst = xn + (size_t)row * DIM;
    #pragma unroll
    for (int i = 0; i < 4; i++) {
        uint2 o;
        o.x = (unsigned)f2bf(v[i].x * inv) | ((unsigned)f2bf(v[i].y * inv) << 16);
        o.y = (unsigned)f2bf(v[i].z * inv) | ((unsigned)f2bf(v[i].w * inv) << 16);
        *(uint2*)(dst + (size_t)(lane + 64 * i) * 4) = o;
    }
}

// ------- Kernel B: symmetric gram, 128x256 half-tiles, 4 waves, BK=32,
// 3-buffer rotation staging kt+2, counted vmcnt(6), raw barriers. 72 KB LDS
// -> 2 independent blocks/CU. Swizzle: chunk j of row r at slot j^((r>>1)&3)
// [R5/R6-verified conflict-free]. Fused top-2 epilogue (row + col sides).
__global__ __launch_bounds__(256, 2) void kgram(const unsigned short* __restrict__ xn,
                                                float2* __restrict__ top2) {
    __shared__ __align__(16) char smem[73728];   // 3 x (A 8KB | B 16KB)
    float (*st2r)[128][2] = (float (*)[128][2])(smem);  // overlay (buf0, post-loop)

    const int t = threadIdx.x;
    const int lane = t & 63;
    const int w = t >> 6;            // 0..3 = column-group of this wave
    const int g = lane >> 4, c = lane & 15;
    const int cswz = (c >> 1) & 3;

    // XCD-bijective swizzle: 1056 = 8 * 132; halves of a tile stay adjacent
    const int bswz = (blockIdx.x & 7) * 132 + (blockIdx.x >> 3);
    const int tix = bswz >> 1, hh = bswz & 1;
    int by = (int)((sqrtf(8.0f * (float)tix + 1.0f) - 1.0f) * 0.5f);
    while ((by + 1) * (by + 2) / 2 <= tix) by++;
    while (by * (by + 1) / 2 > tix) by--;
    const int bx = tix - by * (by + 1) / 2;
    const bool diagTile = (bx == by);

    // staging source pointers: thread covers stored chunk t (+256,.. pattern)
    const int r0 = t >> 2;
    const int c0 = (t & 3) ^ ((r0 >> 1) & 3);
    const unsigned short* gA0p = xn + (size_t)(by * BT + hh * 128 + r0) * DIM + c0 * 8;
    const unsigned short* gB0p = xn + (size_t)(bx * BT + r0) * DIM + c0 * 8;

    // read-side fragment base (bytes, within a region)
    const int aBase = c * 64 + ((g ^ cswz) & 3) * 16;

    f32x4 acc[8][4];
    #pragma unroll
    for (int m = 0; m < 8; m++)
        #pragma unroll
        for (int n = 0; n < 4; n++) acc[m][n] = (f32x4)0.0f;

    bf16x8 aX0, aX1, aX2, aX3, aY0, aY1, aY2, aY3, bX0, bX1, bX2, bX3;

#define STG_A(BUF, KT) do {                                  \
        char* _d = smem + (BUF) * 24576 + t * 16;            \
        const unsigned short* _s = gA0p + (KT) * BK;         \
        gld16(_s, _d);                                       \
        gld16(_s + 65536, _d + 4096);                        \
    } while (0)
#define STG_B(BUF, KT) do {                                  \
        char* _d = smem + (BUF) * 24576 + 8192 + t * 16;     \
        const unsigned short* _s = gB0p + (KT) * BK;         \
        gld16(_s, _d);                                       \
        gld16(_s + 65536,  _d + 4096);                       \
        gld16(_s + 131072, _d + 8192);                       \
        gld16(_s + 196608, _d + 12288);                      \
    } while (0)
#define LDA4(D0, D1, D2, D3, BUF, MH) do {                              \
        const char* _p = smem + (BUF) * 24576 + (MH) * 4096 + aBase;    \
        D0 = *(const bf16x8*)(_p);                                      \
        D1 = *(const bf16x8*)(_p + 1024);                               \
        D2 = *(const bf16x8*)(_p + 2048);                               \
        D3 = *(const bf16x8*)(_p + 3072);                               \
    } while (0)
#define LDB4(D0, D1, D2, D3, BUF) do {                                  \
        const char* _p = smem + (BUF) * 24576 + 8192 + w * 4096 + aBase; \
        D0 = *(const bf16x8*)(_p);                                      \
        D1 = *(const bf16x8*)(_p + 1024);                               \
        D2 = *(const bf16x8*)(_p + 2048);                               \
        D3 = *(const bf16x8*)(_p + 3072);                               \
    } while (0)
#define MF(a, b, cc) __builtin_amdgcn_mfma_f32_16x16x32_bf16(a, b, cc, 0, 0, 0)
#define MQUAD(MB, A0_, A1_, A2_, A3_) do {                                                    \
        acc[(MB)+0][0]=MF(A0_,bX0,acc[(MB)+0][0]); acc[(MB)+0][1]=MF(A0_,bX1,acc[(MB)+0][1]); \
        acc[(MB)+0][2]=MF(A0_,bX2,acc[(MB)+0][2]); acc[(MB)+0][3]=MF(A0_,bX3,acc[(MB)+0][3]); \
        acc[(MB)+1][0]=MF(A1_,bX0,acc[(MB)+1][0]); acc[(MB)+1][1]=MF(A1_,bX1,acc[(MB)+1][1]); \
        acc[(MB)+1][2]=MF(A1_,bX2,acc[(MB)+1][2]); acc[(MB)+1][3]=MF(A1_,bX3,acc[(MB)+1][3]); \
        acc[(MB)+2][0]=MF(A2_,bX0,acc[(MB)+2][0]); acc[(MB)+2][1]=MF(A2_,bX1,acc[(MB)+2][1]); \
        acc[(MB)+2][2]=MF(A2_,bX2,acc[(MB)+2][2]); acc[(MB)+2][3]=MF(A2_,bX3,acc[(MB)+2][3]); \
        acc[(MB)+3][0]=MF(A3_,bX0,acc[(MB)+3][0]); acc[(MB)+3][1]=MF(A3_,bX1,acc[(MB)+3][1]); \
        acc[(MB)+3][2]=MF(A3_,bX2,acc[(MB)+3][2]); acc[(MB)+3][3]=MF(A3_,bX3,acc[(MB)+3][3]); \
    } while (0)
#define BAR1_LGKM                                          \
        __builtin_amdgcn_sched_barrier(0);                 \
        __builtin_amdgcn_s_barrier();                      \
        asm volatile("s_waitcnt lgkmcnt(0)" ::: "memory"); \
        __builtin_amdgcn_sched_barrier(0)
#define ENDPH                                              \
        __builtin_amdgcn_sched_barrier(0);                 \
        __builtin_amdgcn_s_barrier()
#define ENDPH_VM(N)                                        \
        __builtin_amdgcn_sched_barrier(0);                 \
        asm volatile("s_waitcnt vmcnt(" #N ")" ::: "memory"); \
        __builtin_amdgcn_s_barrier()

// One K-step = 2 phases. Stage step J+2 into buf (J+2)%3 during step J.
// 6 gld16/thread/step -> 12 outstanding at step end; vmcnt(6) retires J-1's
// (= step J+1's data). vmcnt placed before the closing barrier (block-wide).
#define KSTEP(J, BUF, SBUF, DOSTG, ENDM)            \
    do {                                            \
        LDA4(aX0, aX1, aX2, aX3, BUF, 0);           \
        LDB4(bX0, bX1, bX2, bX3, BUF);              \
        if (DOSTG) STG_A(SBUF, (J) + 2);            \
        BAR1_LGKM;                                  \
        __builtin_amdgcn_s_setprio(1);              \
        MQUAD(0, aX0, aX1, aX2, aX3);               \
        __builtin_amdgcn_s_setprio(0);              \
        ENDPH;                                      \
        LDA4(aY0, aY1, aY2, aY3, BUF, 1);           \
        if (DOSTG) STG_B(SBUF, (J) + 2);            \
        BAR1_LGKM;                                  \
        __builtin_amdgcn_s_setprio(1);              \
        MQUAD(4, aY0, aY1, aY2, aY3);               \
        __builtin_amdgcn_s_setprio(0);              \
        ENDM;                                       \
    } while (0)

    // prologue: stage steps 0,1; retire step 0 (6 newest = step 1's)
    STG_A(0, 0); STG_B(0, 0);
    STG_A(1, 1); STG_B(1, 1);
    __builtin_amdgcn_sched_barrier(0);
    asm volatile("s_waitcnt vmcnt(6)" ::: "memory");
    __builtin_amdgcn_s_barrier();
    __builtin_amdgcn_sched_barrier(0);

    // steps 0..29 stage (j+2 <= 31); steps 30,31 drain
    #pragma unroll 1
    for (int jj = 0; jj < 10; ++jj) {
        KSTEP(3 * jj + 0, 0, 2, 1, ENDPH_VM(6));
        KSTEP(3 * jj + 1, 1, 0, 1, ENDPH_VM(6));
        KSTEP(3 * jj + 2, 2, 1, 1, ENDPH_VM(6));
    }
    KSTEP(30, 0, 0, 0, ENDPH_VM(0));
    KSTEP(31, 1, 0, 0, (void)0);

#undef KSTEP
#undef ENDPH_VM
#undef ENDPH
#undef BAR1_LGKM
#undef MQUAD
#undef MF
#undef LDB4
#undef LDA4
#undef STG_B
#undef STG_A

    // ---- per-row top-2 (this half's 128 rows, over the 256-col chunk) ----
    // C frag: row = m*16 + g*4 + rr, col = w*64 + n*16 + c
    #pragma unroll
    for (int m = 0; m < 8; m++) {
        #pragma unroll
        for (int rr = 0; rr < 4; rr++) {
            const int lrow = m * 16 + g * 4 + rr;
            float a1 = -1e30f, a2 = -1e30f;
            #pragma unroll
            for (int n = 0; n < 4; n++) {
                float v = acc[m][n][rr];
                if (diagTile && (w * 64 + n * 16 + c) == hh * 128 + lrow) v = -2.0f;
                t2push(a1, a2, v);
            }
            { float b1 = dppror<1>(a1), b2 = dppror<1>(a2); t2merge(a1, a2, b1, b2); }
            { float b1 = dppror<2>(a1), b2 = dppror<2>(a2); t2merge(a1, a2, b1, b2); }
            { float b1 = dppror<4>(a1), b2 = dppror<4>(a2); t2merge(a1, a2, b1, b2); }
            { float b1 = dppror<8>(a1), b2 = dppror<8>(a2); t2merge(a1, a2, b1, b2); }
            if (c == 0) { st2r[w][lrow][0] = a1; st2r[w][lrow][1] = a2; }
        }
    }
    // ---- per-col top-2 (rows of bx-chunk via symmetry; skip diag) ----
    // slot = 2*by + hh (>= 2*bx+2 since by>bx) — no collision with row slots
    if (!diagTile) {
        #pragma unroll
        for (int n = 0; n < 4; n++) {
            float a1 = -1e30f, a2 = -1e30f;
            #pragma unroll
            for (int m = 0; m < 8; m++)
                #pragma unroll
                for (int rr = 0; rr < 4; rr++)
                    t2push(a1, a2, acc[m][n][rr]);
            #pragma unroll
            for (int d = 16; d < 64; d <<= 1) {
                float b1 = __shfl_xor(a1, d);
                float b2 = __shfl_xor(a2, d);
                t2merge(a1, a2, b1, b2);
            }
            if (g == 0)
                top2[(size_t)(bx * BT + w * 64 + n * 16 + c) * SLOTS + 2 * by + hh] =
                    make_float2(a1, a2);
        }
    }
    __syncthreads();
    if (t < 128) {
        float a1 = st2r[0][t][0], a2 = st2r[0][t][1];
        t2merge(a1, a2, st2r[1][t][0], st2r[1][t][1]);
        t2merge(a1, a2, st2r[2][t][0], st2r[2][t][1]);
        t2merge(a1, a2, st2r[3][t][0], st2r[3][t][1]);
        top2[(size_t)(by * BT + hh * 128 + t) * SLOTS + 2 * bx] = make_float2(a1, a2);
    }
}

// ------- Kernel C: wave per row (lane<->slot), loss/gate, device-scope
// atomic reduce; last block computes the final scalar (counter pattern) -------
__global__ __launch_bounds__(256) void kloss(const float2* __restrict__ top2,
                                             float* __restrict__ red,
                                             float* __restrict__ out) {
    const int t = threadIdx.x;
    const int w = t >> 6, lane = t & 63;
    const int row = blockIdx.x * 4 + w;   // 2048 blocks x 4 waves
    const int cr = row >> 8;              // row's column-chunk
    // valid slots: all even; odd slot 2*by'+1 valid iff by' > cr
    const bool valid = !((lane & 1) && ((lane >> 1) <= cr));
    float a1 = -1e30f, a2 = -1e30f;
    if (valid) {
        float2 q = top2[(size_t)row * SLOTS + lane];
        a1 = q.x; a2 = q.y;
    }
    #pragma unroll
    for (int d = 1; d < 64; d <<= 1) {
        float b1 = __shfl_xor(a1, d);
        float b2 = __shfl_xor(a2, d);
        t2merge(a1, a2, b1, b2);
    }
    __shared__ float2 wsum[4];
    if (lane == 0) {
        float slg = 0.0f, sg = 0.0f;
        float vs[2] = {a1, a2};
        #pragma unroll
        for (int i = 0; i < 2; i++) {
            float dd = sqrtf(fmaxf(2.0f - 2.0f * vs[i], 0.0f));
            float loss = -logf(dd + 1e-8f);
            float gate = 1.0f / (1.0f + expf(-(loss - 0.5f) * 10.0f));
            slg += loss * gate;
            sg += gate;
        }
        wsum[w] = make_float2(slg, sg);
    }
    __syncthreads();
    if (t == 0) {
        float a = wsum[0].x + wsum[1].x + wsum[2].x + wsum[3].x;
        float b = wsum[0].y + wsum[1].y + wsum[2].y + wsum[3].y;
        atomicAdd(&red[0], a);
        atomicAdd(&red[1], b);
        __threadfence();
        unsigned int old = atomicAdd((unsigned int*)red + 2, 1u);
        if (old == 2047u) {
            // all adds visible: same-address device-scope RMWs are totally ordered
            float A  = atomicAdd(&red[0], 0.0f);
            float Bb = atomicAdd(&red[1], 0.0f);
            float wm = A / 16384.0f;
            float gm = A / fmaxf(Bb, 1.0f);
            out[0] = 0.5f * wm + 0.5f * gm;
        }
    }
}

extern "C" void kernel_launch(void* const* d_in, const int* in_sizes, int n_in,
                              void* d_out, int out_size, void* d_ws, size_t ws_size,
                              hipStream_t stream) {
    const float* x = (const float*)d_in[0];
    unsigned short* xn = (unsigned short*)d_ws;                              // 16 MB
    float2* top2 = (float2*)((char*)d_ws + (size_t)16 * 1024 * 1024);        // 4 MB
    float* red = (float*)((char*)d_ws + (size_t)20 * 1024 * 1024);           // 12 B
    float* out = (float*)d_out;

    knorm<<<NROWS / 4, 256, 0, stream>>>(x, xn, red);
    kgram<<<NBLK, 256, 0, stream>>>(xn, top2);
    kloss<<<2048, 256, 0, stream>>>(top2, red, out);
}

// Round 9
// 168.460 us; speedup vs baseline: 1.4082x; 1.4082x over previous
//
#include <hip/hip_runtime.h>
#include <math.h>

#define NROWS 8192
#define DIM   1024
#define BT    256              // logical tile edge (column span of a block)
#define SLOTS 64               // top2 slots per row: 2 per column-chunk
#define NTRI  528              // 32*33/2 lower-triangle tiles
#define NBLK  1056             // 528 tiles x 2 row-halves
#define NKT   32               // 1024 / BK
#define BK    32               // K per step (64 B per row)

typedef __bf16 bf16x8 __attribute__((ext_vector_type(8)));
typedef float  f32x4  __attribute__((ext_vector_type(4)));

// fp32 -> bf16 (RNE)
__device__ __forceinline__ unsigned short f2bf(float f) {
    unsigned int u = __float_as_uint(f);
    u = (u + 0x7FFFu + ((u >> 16) & 1u)) >> 16;
    return (unsigned short)u;
}

__device__ __forceinline__ void gld16(const void* g, void* l) {
    __builtin_amdgcn_global_load_lds(
        (__attribute__((address_space(1))) void*)g,
        (__attribute__((address_space(3))) void*)l,
        16, 0, 0);
}

template<int N>
__device__ __forceinline__ float dppror(float v) {
    return __int_as_float(__builtin_amdgcn_update_dpp(
        0, __float_as_int(v), 0x120 + N, 0xF, 0xF, false));
}

__device__ __forceinline__ void t2push(float& a1, float& a2, float v) {
    float hi = fmaxf(a1, v);
    float lo = fminf(a1, v);
    a1 = hi;
    a2 = fmaxf(a2, lo);
}

__device__ __forceinline__ void t2merge(float& a1, float& a2, float b1, float b2) {
    float hi = fmaxf(a1, b1);
    float lo = fminf(a1, b1);
    a1 = hi;
    a2 = fmaxf(fmaxf(a2, b2), lo);
}

// ---------------- Kernel A: row L2-normalize, fp32 -> bf16 ----------------
__global__ __launch_bounds__(256) void knorm(const float* __restrict__ x,
                                             unsigned short* __restrict__ xn) {
    const int w = threadIdx.x >> 6, lane = threadIdx.x & 63;
    const int row = blockIdx.x * 4 + w;
    const float4* src = (const float4*)(x + (size_t)row * DIM);
    float4 v[4];
    float ss = 0.0f;
    #pragma unroll
    for (int i = 0; i < 4; i++) {
        v[i] = src[lane + 64 * i];
        ss += v[i].x * v[i].x + v[i].y * v[i].y + v[i].z * v[i].z + v[i].w * v[i].w;
    }
    #pragma unroll
    for (int d = 1; d < 64; d <<= 1) ss += __shfl_xor(ss, d);
    const float inv = 1.0f / fmaxf(sqrtf(ss), 1e-8f);
    unsigned short* dst = xn + (size_t)row * DIM;
    #pragma unroll
    for (int i = 0; i < 4; i++) {
        uint2 o;
        o.x = (unsigned)f2bf(v[i].x * inv) | ((unsigned)f2bf(v[i].y * inv) << 16);
        o.y = (unsigned)f2bf(v[i].z * inv) | ((unsigned)f2bf(v[i].w * inv) << 16);
        *(uint2*)(dst + (size_t)(lane + 64 * i) * 4) = o;
    }
}

// ------- Kernel B: symmetric gram, 128x256 half-tiles, 4 waves, BK=32,
// 3-buffer rotation staging kt+2, counted vmcnt(6), ONE barrier per K-step
// (mid-step barriers removed — race-free per rotation-ledger analysis:
//  step J reads only buf[J%3]; stage targets buf[(J+2)%3]; all reads are
//  register-consumed before the step-end barrier). 72 KB LDS -> 2 blocks/CU.
// Swizzle: chunk j of row r at slot j^((r>>1)&3) [R5/R6/R8: 0 conflicts].
__global__ __launch_bounds__(256, 2) void kgram(const unsigned short* __restrict__ xn,
                                                float2* __restrict__ top2) {
    __shared__ __align__(16) char smem[73728];   // 3 x (A 8KB | B 16KB)
    float (*st2r)[128][2] = (float (*)[128][2])(smem);  // overlay buf0, post-loop

    const int t = threadIdx.x;
    const int lane = t & 63;
    const int w = t >> 6;            // 0..3 = column-group of this wave
    const int g = lane >> 4, c = lane & 15;
    const int cswz = (c >> 1) & 3;

    // XCD-bijective swizzle: 1056 = 8 * 132; halves of a tile stay adjacent
    const int bswz = (blockIdx.x & 7) * 132 + (blockIdx.x >> 3);
    const int tix = bswz >> 1, hh = bswz & 1;
    int by = (int)((sqrtf(8.0f * (float)tix + 1.0f) - 1.0f) * 0.5f);
    while ((by + 1) * (by + 2) / 2 <= tix) by++;
    while (by * (by + 1) / 2 > tix) by--;
    const int bx = tix - by * (by + 1) / 2;
    const bool diagTile = (bx == by);

    // staging source pointers: thread covers stored chunk t (+256.. pattern)
    const int r0 = t >> 2;
    const int c0 = (t & 3) ^ ((r0 >> 1) & 3);
    const unsigned short* gA0p = xn + (size_t)(by * BT + hh * 128 + r0) * DIM + c0 * 8;
    const unsigned short* gB0p = xn + (size_t)(bx * BT + r0) * DIM + c0 * 8;

    // read-side fragment base (bytes, within a region)
    const int aBase = c * 64 + ((g ^ cswz) & 3) * 16;

    f32x4 acc[8][4];
    #pragma unroll
    for (int m = 0; m < 8; m++)
        #pragma unroll
        for (int n = 0; n < 4; n++) acc[m][n] = (f32x4)0.0f;

    bf16x8 aX0, aX1, aX2, aX3, aY0, aY1, aY2, aY3, bX0, bX1, bX2, bX3;

#define STG_A(BUF, KT) do {                                  \
        char* _d = smem + (BUF) * 24576 + t * 16;            \
        const unsigned short* _s = gA0p + (KT) * BK;         \
        gld16(_s, _d);                                       \
        gld16(_s + 65536, _d + 4096);                        \
    } while (0)
#define STG_B(BUF, KT) do {                                  \
        char* _d = smem + (BUF) * 24576 + 8192 + t * 16;     \
        const unsigned short* _s = gB0p + (KT) * BK;         \
        gld16(_s, _d);                                       \
        gld16(_s + 65536,  _d + 4096);                       \
        gld16(_s + 131072, _d + 8192);                       \
        gld16(_s + 196608, _d + 12288);                      \
    } while (0)
#define LDA4(D0, D1, D2, D3, BUF, MH) do {                              \
        const char* _p = smem + (BUF) * 24576 + (MH) * 4096 + aBase;    \
        D0 = *(const bf16x8*)(_p);                                      \
        D1 = *(const bf16x8*)(_p + 1024);                               \
        D2 = *(const bf16x8*)(_p + 2048);                               \
        D3 = *(const bf16x8*)(_p + 3072);                               \
    } while (0)
#define LDB4(D0, D1, D2, D3, BUF) do {                                  \
        const char* _p = smem + (BUF) * 24576 + 8192 + w * 4096 + aBase; \
        D0 = *(const bf16x8*)(_p);                                      \
        D1 = *(const bf16x8*)(_p + 1024);                               \
        D2 = *(const bf16x8*)(_p + 2048);                               \
        D3 = *(const bf16x8*)(_p + 3072);                               \
    } while (0)
#define MF(a, b, cc) __builtin_amdgcn_mfma_f32_16x16x32_bf16(a, b, cc, 0, 0, 0)
#define MQUAD(MB, A0_, A1_, A2_, A3_) do {                                                    \
        acc[(MB)+0][0]=MF(A0_,bX0,acc[(MB)+0][0]); acc[(MB)+0][1]=MF(A0_,bX1,acc[(MB)+0][1]); \
        acc[(MB)+0][2]=MF(A0_,bX2,acc[(MB)+0][2]); acc[(MB)+0][3]=MF(A0_,bX3,acc[(MB)+0][3]); \
        acc[(MB)+1][0]=MF(A1_,bX0,acc[(MB)+1][0]); acc[(MB)+1][1]=MF(A1_,bX1,acc[(MB)+1][1]); \
        acc[(MB)+1][2]=MF(A1_,bX2,acc[(MB)+1][2]); acc[(MB)+1][3]=MF(A1_,bX3,acc[(MB)+1][3]); \
        acc[(MB)+2][0]=MF(A2_,bX0,acc[(MB)+2][0]); acc[(MB)+2][1]=MF(A2_,bX1,acc[(MB)+2][1]); \
        acc[(MB)+2][2]=MF(A2_,bX2,acc[(MB)+2][2]); acc[(MB)+2][3]=MF(A2_,bX3,acc[(MB)+2][3]); \
        acc[(MB)+3][0]=MF(A3_,bX0,acc[(MB)+3][0]); acc[(MB)+3][1]=MF(A3_,bX1,acc[(MB)+3][1]); \
        acc[(MB)+3][2]=MF(A3_,bX2,acc[(MB)+3][2]); acc[(MB)+3][3]=MF(A3_,bX3,acc[(MB)+3][3]); \
    } while (0)
#define ENDPH_VM(N)                                           \
        __builtin_amdgcn_sched_barrier(0);                    \
        asm volatile("s_waitcnt vmcnt(" #N ")" ::: "memory"); \
        __builtin_amdgcn_s_barrier();                         \
        __builtin_amdgcn_sched_barrier(0)

// One K-step, ONE barrier. Issue all 12 ds_reads + 6 staging loads up front;
// compiler inserts counted lgkmcnt before each consuming MFMA (m97-verified).
// vmcnt(6) at step end retires stage(J+1) (6 newest outstanding = stage(J+2)).
#define KSTEP(J, BUF, SBUF, DOSTG, ENDM)            \
    do {                                            \
        LDA4(aX0, aX1, aX2, aX3, BUF, 0);           \
        LDB4(bX0, bX1, bX2, bX3, BUF);              \
        LDA4(aY0, aY1, aY2, aY3, BUF, 1);           \
        if (DOSTG) {                                \
            STG_A(SBUF, (J) + 2);                   \
            STG_B(SBUF, (J) + 2);                   \
        }                                           \
        __builtin_amdgcn_sched_barrier(0);          \
        __builtin_amdgcn_s_setprio(1);              \
        MQUAD(0, aX0, aX1, aX2, aX3);               \
        MQUAD(4, aY0, aY1, aY2, aY3);               \
        __builtin_amdgcn_s_setprio(0);              \
        ENDM;                                       \
    } while (0)

    // prologue: stage steps 0,1; retire step 0 (6 newest = step 1's)
    STG_A(0, 0); STG_B(0, 0);
    STG_A(1, 1); STG_B(1, 1);
    __builtin_amdgcn_sched_barrier(0);
    asm volatile("s_waitcnt vmcnt(6)" ::: "memory");
    __builtin_amdgcn_s_barrier();
    __builtin_amdgcn_sched_barrier(0);

    // steps 0..29 stage (j+2 <= 31); steps 30,31 drain
    #pragma unroll 1
    for (int jj = 0; jj < 10; ++jj) {
        KSTEP(3 * jj + 0, 0, 2, 1, ENDPH_VM(6));
        KSTEP(3 * jj + 1, 1, 0, 1, ENDPH_VM(6));
        KSTEP(3 * jj + 2, 2, 1, 1, ENDPH_VM(6));
    }
    KSTEP(30, 0, 0, 0, ENDPH_VM(0));
    KSTEP(31, 1, 0, 0, (void)0);

#undef KSTEP
#undef ENDPH_VM
#undef MQUAD
#undef MF
#undef LDB4
#undef LDA4
#undef STG_B
#undef STG_A

    // ---- per-row top-2 (this half's 128 rows, over the 256-col chunk) ----
    // C frag: row = m*16 + g*4 + rr, col = w*64 + n*16 + c
    #pragma unroll
    for (int m = 0; m < 8; m++) {
        #pragma unroll
        for (int rr = 0; rr < 4; rr++) {
            const int lrow = m * 16 + g * 4 + rr;
            float a1 = -1e30f, a2 = -1e30f;
            #pragma unroll
            for (int n = 0; n < 4; n++) {
                float v = acc[m][n][rr];
                if (diagTile && (w * 64 + n * 16 + c) == hh * 128 + lrow) v = -2.0f;
                t2push(a1, a2, v);
            }
            { float b1 = dppror<1>(a1), b2 = dppror<1>(a2); t2merge(a1, a2, b1, b2); }
            { float b1 = dppror<2>(a1), b2 = dppror<2>(a2); t2merge(a1, a2, b1, b2); }
            { float b1 = dppror<4>(a1), b2 = dppror<4>(a2); t2merge(a1, a2, b1, b2); }
            { float b1 = dppror<8>(a1), b2 = dppror<8>(a2); t2merge(a1, a2, b1, b2); }
            if (c == 0) { st2r[w][lrow][0] = a1; st2r[w][lrow][1] = a2; }
        }
    }
    // ---- per-col top-2 (rows of bx-chunk via symmetry; skip diag) ----
    // slot = 2*by + hh (>= 2*bx+2 since by>bx) — no collision with row slots
    if (!diagTile) {
        #pragma unroll
        for (int n = 0; n < 4; n++) {
            float a1 = -1e30f, a2 = -1e30f;
            #pragma unroll
            for (int m = 0; m < 8; m++)
                #pragma unroll
                for (int rr = 0; rr < 4; rr++)
                    t2push(a1, a2, acc[m][n][rr]);
            #pragma unroll
            for (int d = 16; d < 64; d <<= 1) {
                float b1 = __shfl_xor(a1, d);
                float b2 = __shfl_xor(a2, d);
                t2merge(a1, a2, b1, b2);
            }
            if (g == 0)
                top2[(size_t)(bx * BT + w * 64 + n * 16 + c) * SLOTS + 2 * by + hh] =
                    make_float2(a1, a2);
        }
    }
    __syncthreads();
    if (t < 128) {
        float a1 = st2r[0][t][0], a2 = st2r[0][t][1];
        t2merge(a1, a2, st2r[1][t][0], st2r[1][t][1]);
        t2merge(a1, a2, st2r[2][t][0], st2r[2][t][1]);
        t2merge(a1, a2, st2r[3][t][0], st2r[3][t][1]);
        top2[(size_t)(by * BT + hh * 128 + t) * SLOTS + 2 * bx] = make_float2(a1, a2);
    }
}

// ------- Kernel C: thread per row over 64 slots (validity-masked), loss/gate,
// block partials. 32 blocks -> no atomic contention (R8 lesson). -------
__global__ __launch_bounds__(256) void kloss(const float2* __restrict__ top2,
                                             float2* __restrict__ partials) {
    const int r = blockIdx.x * 256 + threadIdx.x;   // 0..8191
    const int cr = r >> 8;                          // row's column-chunk
    const float2* p = top2 + (size_t)r * SLOTS;
    float a1 = -1e30f, a2 = -1e30f;
    #pragma unroll 8
    for (int s = 0; s < SLOTS; s++) {
        // valid: even slots always; odd slot 2*by'+1 only if by' > cr
        if (!((s & 1) && ((s >> 1) <= cr))) {
            float2 q = p[s];
            t2merge(a1, a2, q.x, q.y);
        }
    }
    float slg = 0.0f, sg = 0.0f;
    float vs[2] = {a1, a2};
    #pragma unroll
    for (int i = 0; i < 2; i++) {
        float dd = sqrtf(fmaxf(2.0f - 2.0f * vs[i], 0.0f));
        float loss = -logf(dd + 1e-8f);
        float gate = 1.0f / (1.0f + expf(-(loss - 0.5f) * 10.0f));
        slg += loss * gate;
        sg += gate;
    }
    #pragma unroll
    for (int d = 1; d < 64; d <<= 1) {
        slg += __shfl_xor(slg, d);
        sg  += __shfl_xor(sg, d);
    }
    __shared__ float2 wsum[4];
    if ((threadIdx.x & 63) == 0) wsum[threadIdx.x >> 6] = make_float2(slg, sg);
    __syncthreads();
    if (threadIdx.x == 0) {
        float a = 0.0f, b = 0.0f;
        #pragma unroll
        for (int i = 0; i < 4; i++) { a += wsum[i].x; b += wsum[i].y; }
        partials[blockIdx.x] = make_float2(a, b);
    }
}

// ---------------- Kernel D: final scalar over 32 partials ----------------
__global__ void kfinal(const float2* __restrict__ partials, float* __restrict__ out) {
    const int t = threadIdx.x;  // 64 threads
    float a = 0.0f, b = 0.0f;
    if (t < 32) { float2 p = partials[t]; a = p.x; b = p.y; }
    #pragma unroll
    for (int d = 1; d < 64; d <<= 1) {
        a += __shfl_xor(a, d);
        b += __shfl_xor(b, d);
    }
    if (t == 0) {
        float wm = a / 16384.0f;
        float gm = a / fmaxf(b, 1.0f);
        out[0] = 0.5f * wm + 0.5f * gm;
    }
}

extern "C" void kernel_launch(void* const* d_in, const int* in_sizes, int n_in,
                              void* d_out, int out_size, void* d_ws, size_t ws_size,
                              hipStream_t stream) {
    const float* x = (const float*)d_in[0];
    unsigned short* xn = (unsigned short*)d_ws;                              // 16 MB
    float2* top2 = (float2*)((char*)d_ws + (size_t)16 * 1024 * 1024);        // 4 MB
    float2* partials = (float2*)((char*)d_ws + (size_t)20 * 1024 * 1024);    // 256 B
    float* out = (float*)d_out;

    knorm<<<NROWS / 4, 256, 0, stream>>>(x, xn);
    kgram<<<NBLK, 256, 0, stream>>>(xn, top2);
    kloss<<<32, 256, 0, stream>>>(top2, partials);
    kfinal<<<1, 64, 0, stream>>>(partials, out);
}